// Round 2
// baseline (34.288 us; speedup 1.0000x reference)
//
#include <hip/hip_runtime.h>

#define B_ROWS 4194304
#define NTHREADS 256
#define TASKS_PER_BLOCK NTHREADS              // 1 task = 5 float4 = 4 rows
#define NBLOCKS ((B_ROWS / 4) / TASKS_PER_BLOCK)   // 4096
#define F4_PER_BLOCK (TASKS_PER_BLOCK * 5)    // 1280 float4 = 20 KB per tensor

// Stage 1: coalesced global loads -> LDS -> per-task row math -> block partial.
__global__ __launch_bounds__(NTHREADS) void loss_partial_kernel(
    const float* __restrict__ outp,
    const float* __restrict__ tgt,
    const float* __restrict__ dist,
    float* __restrict__ partials)
{
    __shared__ float4 lt[F4_PER_BLOCK];   // 20 KB
    __shared__ float4 lo[F4_PER_BLOCK];   // 20 KB

    float dd[5];
    #pragma unroll
    for (int c = 0; c < 5; ++c) dd[c] = dist[c];

    const float4* tp4 = (const float4*)tgt;
    const float4* op4 = (const float4*)outp;

    const int tid = threadIdx.x;
    const long base = (long)blockIdx.x * F4_PER_BLOCK;

    // Fully coalesced: lane-contiguous float4 indices. Issue all 10 loads,
    // then write to LDS (reg-staged).
    float4 tv[5], ov[5];
    #pragma unroll
    for (int j = 0; j < 5; ++j) tv[j] = tp4[base + j * NTHREADS + tid];
    #pragma unroll
    for (int j = 0; j < 5; ++j) ov[j] = op4[base + j * NTHREADS + tid];
    #pragma unroll
    for (int j = 0; j < 5; ++j) lt[j * NTHREADS + tid] = tv[j];
    #pragma unroll
    for (int j = 0; j < 5; ++j) lo[j * NTHREADS + tid] = ov[j];
    __syncthreads();

    // Each thread now reads its own task (5 consecutive float4 = 4 rows)
    // from LDS. 80 B lane stride -> period-8 bank pattern, conflict-free.
    float4 t0 = lt[tid * 5 + 0], t1 = lt[tid * 5 + 1], t2 = lt[tid * 5 + 2],
           t3 = lt[tid * 5 + 3], t4 = lt[tid * 5 + 4];
    float4 o0 = lo[tid * 5 + 0], o1 = lo[tid * 5 + 1], o2 = lo[tid * 5 + 2],
           o3 = lo[tid * 5 + 3], o4 = lo[tid * 5 + 4];

    float tr[4][5] = {
        {t0.x, t0.y, t0.z, t0.w, t1.x},
        {t1.y, t1.z, t1.w, t2.x, t2.y},
        {t2.z, t2.w, t3.x, t3.y, t3.z},
        {t3.w, t4.x, t4.y, t4.z, t4.w}};
    float orr[4][5] = {
        {o0.x, o0.y, o0.z, o0.w, o1.x},
        {o1.y, o1.z, o1.w, o2.x, o2.y},
        {o2.z, o2.w, o3.x, o3.y, o3.z},
        {o3.w, o4.x, o4.y, o4.z, o4.w}};

    float acc = 0.0f;
    #pragma unroll
    for (int r = 0; r < 4; ++r) {
        // first-occurrence argmax (matches jnp.argmax) -> delta
        float m = tr[r][0];
        float delta = dd[0];
        #pragma unroll
        for (int c = 1; c < 5; ++c) {
            if (tr[r][c] > m) { m = tr[r][c]; delta = dd[c]; }
        }
        #pragma unroll
        for (int c = 0; c < 5; ++c) {
            acc += (orr[r][c] - tr[r][c]) * (fabsf(dd[c] - delta) + 1.0f);
        }
    }

    // Wave (64-lane) shuffle reduce, then cross-wave via LDS.
    #pragma unroll
    for (int off = 32; off > 0; off >>= 1) acc += __shfl_down(acc, off, 64);

    __shared__ float smem[NTHREADS / 64];
    const int lane = tid & 63;
    const int wid  = tid >> 6;
    if (lane == 0) smem[wid] = acc;
    __syncthreads();
    if (tid == 0) {
        float s = 0.0f;
        #pragma unroll
        for (int w = 0; w < NTHREADS / 64; ++w) s += smem[w];
        partials[blockIdx.x] = s;
    }
}

// Stage 2: reduce NBLOCKS partials, divide by B.
__global__ __launch_bounds__(NTHREADS) void loss_final_kernel(
    const float* __restrict__ partials,
    float* __restrict__ out)
{
    float acc = 0.0f;
    for (int i = threadIdx.x; i < NBLOCKS; i += NTHREADS) acc += partials[i];

    #pragma unroll
    for (int off = 32; off > 0; off >>= 1) acc += __shfl_down(acc, off, 64);

    __shared__ float smem[NTHREADS / 64];
    const int lane = threadIdx.x & 63;
    const int wid  = threadIdx.x >> 6;
    if (lane == 0) smem[wid] = acc;
    __syncthreads();
    if (threadIdx.x == 0) {
        float s = 0.0f;
        #pragma unroll
        for (int w = 0; w < NTHREADS / 64; ++w) s += smem[w];
        out[0] = s / (float)B_ROWS;
    }
}

extern "C" void kernel_launch(void* const* d_in, const int* in_sizes, int n_in,
                              void* d_out, int out_size, void* d_ws, size_t ws_size,
                              hipStream_t stream)
{
    const float* outp = (const float*)d_in[0];   // output [B,5] f32
    const float* tgt  = (const float*)d_in[1];   // target [B,5] f32
    const float* dist = (const float*)d_in[2];   // distance [5] f32
    float* out = (float*)d_out;                  // scalar f32
    float* partials = (float*)d_ws;              // NBLOCKS floats of scratch

    loss_partial_kernel<<<NBLOCKS, NTHREADS, 0, stream>>>(outp, tgt, dist, partials);
    loss_final_kernel<<<1, NTHREADS, 0, stream>>>(partials, out);
}